// Round 8
// baseline (322.710 us; speedup 1.0000x reference)
//
#include <hip/hip_runtime.h>
#include <hip/hip_bf16.h>

#define BB   64
#define CING 96
#define MIDC 192
#define HH   56
#define WWD  56
#define HWSZ (HH*WWD)
#define COUTC 96
#define BNEPS 1e-5f

typedef __attribute__((ext_vector_type(8))) short short8;
typedef __attribute__((ext_vector_type(8))) unsigned short ushort8v;
typedef __attribute__((ext_vector_type(4))) float float4v;
typedef unsigned short ushort_t;
typedef unsigned int uint_t;

__device__ __forceinline__ float siluf(float v){
    return v * __builtin_amdgcn_rcpf(1.f + __expf(-v));
}
__device__ __forceinline__ float sigmf(float v){
    return __builtin_amdgcn_rcpf(1.f + __expf(-v));
}
__device__ __forceinline__ ushort_t f2bs(float f){
    uint_t u = __float_as_uint(f);
    uint_t r = u + 0x7FFFu + ((u >> 16) & 1u);   // RNE; inputs are finite
    return (ushort_t)(r >> 16);
}
__device__ __forceinline__ float bs2f(ushort_t u){
    return __uint_as_float(((uint_t)u) << 16);
}
__device__ __forceinline__ uint_t pkbf(float a, float b){   // packed bf16 cvt (RNE)
    __hip_bfloat162 h = __float22bfloat162_rn(make_float2(a, b));
    union { __hip_bfloat162 h; uint_t u; } cv; cv.h = h; return cv.u;
}
__device__ __forceinline__ float bslo(uint_t x){ return __uint_as_float(x << 16); }
__device__ __forceinline__ float bshi(uint_t x){ return __uint_as_float(x & 0xFFFF0000u); }

// ================ k1: expand GEMM (MFMA) + BN-fold + SiLU -> E =================
// Weight fold (ex-k0) done in-block; C epilogue staged via LDS for coalesced stores.
#define LDB1T 104
#define LDC1  72      // u16 stride; 144 B (16B-aligned), q-group conflicts <= 4-way
__global__ __launch_bounds__(256) void k1_expand(
    const float* __restrict__ x,
    const float* __restrict__ expand_w,
    const float* __restrict__ expand_bn,
    ushort_t* __restrict__ EY)
{
    __shared__ __align__(16) char smem[MIDC*LDC1*2];    // 27,648 B (BsT overlaid)
    __shared__ float scL[MIDC], ebL[MIDC];
    ushort_t* BsT = (ushort_t*)smem;                    // [n=64][k] stride LDB1T
    ushort_t* Cs  = (ushort_t*)smem;                    // [m=192][px] stride LDC1
    const int t = threadIdx.x;
    const int p0 = blockIdx.x*64, b = blockIdx.y;

    if (t < MIDC) {                                     // BN fold (ex-k0)
        int ic = (t&3)*48 + (t>>2);
        float sc = expand_bn[ic] * rsqrtf(expand_bn[3*MIDC+ic] + BNEPS);
        scL[t] = sc;
        ebL[t] = expand_bn[MIDC+ic] - expand_bn[2*MIDC+ic]*sc;
    }
    {                                                   // stage B transposed: [n=64][k=96]
        const int n  = t & 63;
        const int kb = (t >> 6)*24;
        #pragma unroll
        for (int ii = 0; ii < 3; ii++) {
            int k8 = kb + ii*8;
            const float* xp = x + ((size_t)(b*CING + k8))*HWSZ + p0 + n;
            float v[8];
            #pragma unroll
            for (int j = 0; j < 8; j++) v[j] = xp[(size_t)j*HWSZ];
            uint4 uu;
            uu.x = pkbf(v[0],v[1]); uu.y = pkbf(v[2],v[3]);
            uu.z = pkbf(v[4],v[5]); uu.w = pkbf(v[6],v[7]);
            *(uint4*)(&BsT[n*LDB1T + k8]) = uu;
        }
    }
    __syncthreads();

    const int lane = t & 63, wv = t >> 6;
    const int l = lane & 15, q = lane >> 4;
    short8 af[3][3];                                    // A on the fly (L2-hot weights)
    #pragma unroll
    for (int mi = 0; mi < 3; mi++) {
        const int m = (wv*3+mi)*16 + l;
        const float sc = scL[m];
        const float* wp = expand_w + (size_t)((m&3)*48 + (m>>2))*CING + q*8;
        #pragma unroll
        for (int ks = 0; ks < 3; ks++) {
            float4 v0 = *(const float4*)(wp + ks*32);
            float4 v1 = *(const float4*)(wp + ks*32 + 4);
            union { uint4 u; short8 s; } cv;
            cv.u.x = pkbf(v0.x*sc, v0.y*sc); cv.u.y = pkbf(v0.z*sc, v0.w*sc);
            cv.u.z = pkbf(v1.x*sc, v1.y*sc); cv.u.w = pkbf(v1.z*sc, v1.w*sc);
            af[ks][mi] = cv.s;
        }
    }

    float4v acc[3][4];
    #pragma unroll
    for (int mi=0;mi<3;mi++)
        #pragma unroll
        for (int nt=0;nt<4;nt++) acc[mi][nt] = (float4v){0.f,0.f,0.f,0.f};
    #pragma unroll
    for (int ks = 0; ks < 3; ks++) {
        const int k0 = ks*32;
        short8 bf[4];
        #pragma unroll
        for (int nt = 0; nt < 4; nt++)
            bf[nt] = *(const short8*)(&BsT[(nt*16 + l)*LDB1T + k0 + q*8]);
        #pragma unroll
        for (int mi = 0; mi < 3; mi++)
            #pragma unroll
            for (int nt = 0; nt < 4; nt++)
                acc[mi][nt] = __builtin_amdgcn_mfma_f32_16x16x32_bf16(af[ks][mi], bf[nt], acc[mi][nt], 0,0,0);
    }
    __syncthreads();                                    // BsT dead; reuse as Cs
    #pragma unroll
    for (int mi = 0; mi < 3; mi++) {
        #pragma unroll
        for (int r = 0; r < 4; r++) {
            const int m = (wv*3+mi)*16 + q*4 + r;
            const float eb = ebL[m];
            #pragma unroll
            for (int nt = 0; nt < 4; nt++)
                Cs[m*LDC1 + nt*16 + l] = f2bs(siluf(acc[mi][nt][r] + eb));
        }
    }
    __syncthreads();
    #pragma unroll
    for (int i = 0; i < 6; i++) {                       // coalesced readout
        int ch = i*256 + t;
        int row = ch >> 3, seg = ch & 7;
        uint4 v = *(const uint4*)(&Cs[row*LDC1 + seg*8]);
        *(uint4*)(EY + (size_t)(b*MIDC + row)*HWSZ + p0 + seg*8) = v;
    }
}

// ================ k2: shifted dw3x3 + SiLU, unroll-2, in-place =================
template<int DY, int DX>
__device__ __forceinline__ float dw_plane(
    ushort_t* __restrict__ plane, const float* __restrict__ w9, float cst,
    int li, int h, bool act)
{
    uint2 pA = make_uint2(0u,0u), pB = make_uint2(0u,0u);
    int rA = -100, rB = -100;
    if (h == 0) { if (DY==1){ rA=28; rB=29; } else if (DY==0){ rA=28; } }
    else        { if (DY==-1){ rA=26; rB=27; } else if (DY==0){ rA=27; } }
    const ushort_t* pl = plane + li*4;
    if (rA >= 0) pA = *(const uint2*)(pl + rA*WWD);
    if (rB >= 0) pB = *(const uint2*)(pl + rB*WWD);
    __syncthreads();

    const int ys = h ? 27 : -1;
    const int so = h ? 29 : 1;

    auto loadrow = [&](int y) -> uint2 {
        int yy = y + DY;
        uint2 u = make_uint2(0u,0u);
        if (((unsigned)y < (unsigned)HH) && ((unsigned)yy < (unsigned)HH)) {
            if (yy == rA)      u = pA;
            else if (yy == rB) u = pB;
            else               u = *(const uint2*)(pl + yy*WWD);
        }
        return u;
    };

    float p0v[4] = {0,0,0,0}, p1v[4] = {0,0,0,0};
    float partial = 0.f;

    auto process = [&](uint2 u, int y) {
        uint_t lhi = __shfl_up(u.y, 1);
        uint_t rlo = __shfl_down(u.x, 1);
        if (li == 0)  lhi = 0u;
        if (li == 13) rlo = 0u;
        float s[8];
        s[0]=bslo(lhi); s[1]=bshi(lhi);
        s[2]=bslo(u.x); s[3]=bshi(u.x);
        s[4]=bslo(u.y); s[5]=bshi(u.y);
        s[6]=bslo(rlo); s[7]=bshi(rlo);
        if (li == 0)  s[DX+1] = 0.f;
        if (li == 13) s[DX+6] = 0.f;
        float o[4];
        #pragma unroll
        for (int j = 0; j < 4; j++) {
            float t0 = s[j+DX+1], t1 = s[j+DX+2], t2 = s[j+DX+3];
            o[j]   = p1v[j] + (w9[6]*t0 + w9[7]*t1 + w9[8]*t2) + cst;
            p1v[j] = p0v[j] + (w9[3]*t0 + w9[4]*t1 + w9[5]*t2);
            p0v[j] =           w9[0]*t0 + w9[1]*t1 + w9[2]*t2;
        }
        if (y >= so && act) {
            float y0=siluf(o[0]), y1=siluf(o[1]), y2=siluf(o[2]), y3=siluf(o[3]);
            uint2 w2; w2.x = pkbf(y0,y1); w2.y = pkbf(y2,y3);
            *(uint2*)(plane + (size_t)(y-1)*WWD + li*4) = w2;
            partial += (y0+y1) + (y2+y3);
        }
    };

    uint2 u  = loadrow(ys);
    uint2 un = loadrow(ys+1);
    #pragma unroll
    for (int k = 0; k < 15; k++) {
        const int y = ys + 2*k;
        uint2 u2 = loadrow(y+2);        // prefetch pair (before any store this pair)
        uint2 u3 = loadrow(y+3);
        process(u,  y);
        process(un, y+1);
        u = u2; un = u3;
    }
    #pragma unroll
    for (int off = 1; off < 16; off <<= 1) partial += __shfl_xor(partial, off);
    return partial;
}

__global__ __launch_bounds__(128) void k2_dw(
    ushort_t* __restrict__ EY,
    const float* __restrict__ dw_w,  const float* __restrict__ dw_bn,
    const float* __restrict__ id_w,  const float* __restrict__ id_bn,
    const float* __restrict__ merge_bn,
    float* __restrict__ sums)
{
    __shared__ float wred[8];
    const int t = threadIdx.x;
    const int lane = t & 63, h = t >> 6;
    const int lg = lane >> 4, li = lane & 15;
    const int gi = blockIdx.x >> 2, r = blockIdx.x & 3;   // r = shift group (uniform)
    const int b = blockIdx.y;
    const int oc = gi*16 + r + lg*4;
    ushort_t* plane = EY + (size_t)(b*MIDC + oc)*HWSZ;

    // BN fold (ex-k0), per lane (broadcast loads, L2-hot)
    float sc1 = dw_bn[oc]    * rsqrtf(dw_bn[3*MIDC+oc]    + BNEPS);
    float sh1 = dw_bn[MIDC+oc]    - dw_bn[2*MIDC+oc]*sc1;
    float sc2 = id_bn[oc]    * rsqrtf(id_bn[3*MIDC+oc]    + BNEPS);
    float sh2 = id_bn[MIDC+oc]    - id_bn[2*MIDC+oc]*sc2;
    float sc3 = merge_bn[oc] * rsqrtf(merge_bn[3*MIDC+oc] + BNEPS);
    float sh3 = merge_bn[MIDC+oc] - merge_bn[2*MIDC+oc]*sc3;
    float A = sc3*sc1;
    float w9[9];
    #pragma unroll
    for (int j = 0; j < 9; j++) w9[j] = A*dw_w[oc*9+j];
    w9[4] += sc3*sc2*id_w[oc];
    const float cst = sc3*(sh1+sh2) + sh3;

    const bool act = (li < 14);
    float ps;
    if      (r == 0) ps = dw_plane<-1, 0>(plane, w9, cst, li, h, act);
    else if (r == 1) ps = dw_plane< 0,-1>(plane, w9, cst, li, h, act);
    else if (r == 2) ps = dw_plane< 1, 0>(plane, w9, cst, li, h, act);
    else             ps = dw_plane< 0, 1>(plane, w9, cst, li, h, act);
    if (li == 0) wred[h*4 + lg] = ps;
    __syncthreads();
    if (t < 4) sums[b*MIDC + gi*16 + r + t*4] = wred[t] + wred[4 + t];
}

// ================ k4: SE (in-block) + proj GEMM + BN + residual + SiLU =========
#define LDB4T 200
#define LDC4  68      // f32 stride; 272 B (16B-aligned)
__global__ __launch_bounds__(256) void k4_proj(
    const ushort_t* __restrict__ EY,
    const float* __restrict__ sums,
    const float* __restrict__ se_red_w, const float* __restrict__ se_red_b,
    const float* __restrict__ se_exp_w, const float* __restrict__ se_exp_b,
    const float* __restrict__ proj_w,   const float* __restrict__ proj_bn,
    const float* __restrict__ x,
    float* __restrict__ out)
{
    __shared__ __align__(16) char smem[COUTC*LDC4*4];    // 26,112 B (BsT overlaid)
    __shared__ float meanL[MIDC], redL[24], seL[MIDC];
    __shared__ float pscL[COUTC], pshL[COUTC];
    ushort_t* BsT = (ushort_t*)smem;                     // [n=64][k=192] stride LDB4T
    float*    Cs4 = (float*)smem;                        // [m=96][px=64] stride LDC4
    const int t = threadIdx.x;
    const int p0 = blockIdx.x*64, b = blockIdx.y;

    // ---- SE MLP (ex-k3), redundant per block ----
    if (t < MIDC) meanL[t] = sums[b*MIDC + t] * (1.f/(float)HWSZ);
    if (t < COUTC) {
        float sc = proj_bn[t] * rsqrtf(proj_bn[3*COUTC+t] + BNEPS);
        pscL[t] = sc;
        pshL[t] = proj_bn[COUTC+t] - proj_bn[2*COUTC+t]*sc;
    }
    __syncthreads();
    if (t < 24) {
        int g = t >> 1;
        float a = se_red_b[t];
        #pragma unroll
        for (int i = 0; i < 16; i++) a += meanL[g*16+i] * se_red_w[t*16+i];
        redL[t] = fmaxf(a, 0.f);
    }
    __syncthreads();
    if (t < MIDC) {
        int g = t >> 4;
        float a = se_exp_b[t] + redL[g*2]*se_exp_w[t*2] + redL[g*2+1]*se_exp_w[t*2+1];
        seL[t] = sigmf(a);
    }
    __syncthreads();

    // ---- stage B transposed, SE folded ----
    {
        const int n  = t & 63;
        const int kb = (t >> 6)*48;
        #pragma unroll
        for (int ii = 0; ii < 6; ii++) {
            int k8 = kb + ii*8;
            const ushort_t* ep = EY + ((size_t)(b*MIDC + k8))*HWSZ + p0 + n;
            float v[8];
            #pragma unroll
            for (int j = 0; j < 8; j++)
                v[j] = bs2f(ep[(size_t)j*HWSZ]) * seL[k8+j];
            uint4 uu;
            uu.x = pkbf(v[0],v[1]); uu.y = pkbf(v[2],v[3]);
            uu.z = pkbf(v[4],v[5]); uu.w = pkbf(v[6],v[7]);
            *(uint4*)(&BsT[n*LDB4T + k8]) = uu;
        }
    }

    const int lane = t & 63, wv = t >> 6;
    const int l = lane & 15, q = lane >> 4;
    const int mh = wv >> 1, nh = wv & 1;
    short8 af[6][3];                                    // A on the fly (L2-hot)
    #pragma unroll
    for (int mi = 0; mi < 3; mi++) {
        const int m = (mh*3+mi)*16 + l;
        const float* wp = proj_w + (size_t)m*MIDC + q*8;
        #pragma unroll
        for (int ks = 0; ks < 6; ks++) {
            float4 v0 = *(const float4*)(wp + ks*32);
            float4 v1 = *(const float4*)(wp + ks*32 + 4);
            union { uint4 u; short8 s; } cv;
            cv.u.x = pkbf(v0.x, v0.y); cv.u.y = pkbf(v0.z, v0.w);
            cv.u.z = pkbf(v1.x, v1.y); cv.u.w = pkbf(v1.z, v1.w);
            af[ks][mi] = cv.s;
        }
    }
    __syncthreads();

    float4v acc[3][2];
    #pragma unroll
    for (int mi=0;mi<3;mi++)
        #pragma unroll
        for (int nt=0;nt<2;nt++) acc[mi][nt] = (float4v){0.f,0.f,0.f,0.f};
    #pragma unroll
    for (int ks = 0; ks < 6; ks++) {
        const int k0 = ks*32;
        short8 bf[2];
        #pragma unroll
        for (int nt = 0; nt < 2; nt++)
            bf[nt] = *(const short8*)(&BsT[(nh*32 + nt*16 + l)*LDB4T + k0 + q*8]);
        #pragma unroll
        for (int mi = 0; mi < 3; mi++)
            #pragma unroll
            for (int nt = 0; nt < 2; nt++)
                acc[mi][nt] = __builtin_amdgcn_mfma_f32_16x16x32_bf16(af[ks][mi], bf[nt], acc[mi][nt], 0,0,0);
    }
    __syncthreads();                                    // BsT dead; reuse as Cs4
    #pragma unroll
    for (int mi = 0; mi < 3; mi++) {
        #pragma unroll
        for (int r = 0; r < 4; r++) {
            const int m = (mh*3+mi)*16 + q*4 + r;
            const float sc = pscL[m], sh = pshL[m];
            #pragma unroll
            for (int nt = 0; nt < 2; nt++)
                Cs4[m*LDC4 + nh*32 + nt*16 + l] = acc[mi][nt][r]*sc + sh;
        }
    }
    __syncthreads();
    #pragma unroll
    for (int i = 0; i < 6; i++) {                       // coalesced residual + store
        int ch = i*256 + t;
        int row = ch >> 4, seg = ch & 15;
        const size_t idx = (size_t)(b*COUTC + row)*HWSZ + p0 + seg*4;
        float4 c = *(const float4*)(&Cs4[row*LDC4 + seg*4]);
        float4 xr = *(const float4*)(x + idx);
        float4 o;
        o.x = siluf(c.x + xr.x); o.y = siluf(c.y + xr.y);
        o.z = siluf(c.z + xr.z); o.w = siluf(c.w + xr.w);
        *(float4*)(out + idx) = o;
    }
}

extern "C" void kernel_launch(void* const* d_in, const int* in_sizes, int n_in,
                              void* d_out, int out_size, void* d_ws, size_t ws_size,
                              hipStream_t stream)
{
    const float* x         = (const float*)d_in[0];
    const float* expand_w  = (const float*)d_in[1];
    const float* expand_bn = (const float*)d_in[2];
    const float* dw_w      = (const float*)d_in[3];
    const float* dw_bn     = (const float*)d_in[4];
    const float* id_w      = (const float*)d_in[5];
    const float* id_bn     = (const float*)d_in[6];
    const float* merge_bn  = (const float*)d_in[7];
    const float* se_red_w  = (const float*)d_in[8];
    const float* se_red_b  = (const float*)d_in[9];
    const float* se_exp_w  = (const float*)d_in[10];
    const float* se_exp_b  = (const float*)d_in[11];
    const float* proj_w    = (const float*)d_in[12];
    const float* proj_bn   = (const float*)d_in[13];

    char* base = (char*)d_ws;
    ushort_t* EY = (ushort_t*)base;                               // 77,070,336 B
    float* sums  = (float*)(base + (size_t)BB*MIDC*HWSZ*2);       // 12,288 f32

    k1_expand<<<dim3(HWSZ/64, BB), dim3(256), 0, stream>>>(
        x, expand_w, expand_bn, EY);
    k2_dw<<<dim3(48, BB), dim3(128), 0, stream>>>(
        EY, dw_w, dw_bn, id_w, id_bn, merge_bn, sums);
    k4_proj<<<dim3(HWSZ/64, BB), dim3(256), 0, stream>>>(
        EY, sums, se_red_w, se_red_b, se_exp_w, se_exp_b,
        proj_w, proj_bn, x, (float*)d_out);
}